// Round 2
// baseline (7322.880 us; speedup 1.0000x reference)
//
#include <hip/hip_runtime.h>
#include <hip/hip_bf16.h>
#include <stdint.h>

#define TT 64
#define BB 512
#define XX 1024
#define HH 1024
#define ZZ 256
#define AA 64

typedef __bf16 bf16;
typedef bf16 bf16x8 __attribute__((ext_vector_type(8)));
typedef float f32x4 __attribute__((ext_vector_type(4)));

// d_out layout (fp32): beliefs[T+1,B,H] | q_loc | q_scale | p_loc | p_scale | z_q (each [T,B,Z])
#define SZ_BEL ((long)(TT + 1) * BB * HH)
#define SZ_TBZ ((long)TT * BB * ZZ)
#define OFF_QL (SZ_BEL)
#define OFF_QS (OFF_QL + SZ_TBZ)
#define OFF_PL (OFF_QL + 2 * SZ_TBZ)
#define OFF_PS (OFF_QL + 3 * SZ_TBZ)
#define OFF_ZQ (OFF_QL + 4 * SZ_TBZ)

#define GLL16(g, l)                                                         \
  __builtin_amdgcn_global_load_lds(                                         \
      (__attribute__((address_space(1))) void*)(g),                         \
      (__attribute__((address_space(3))) void*)(l), 16, 0, 0)

__device__ __forceinline__ float eluf(float x) {
  return x > 0.f ? x : expf(x) - 1.f;
}
__device__ __forceinline__ float splusf(float x) {
  return fmaxf(x, 0.f) + log1pf(expf(-fabsf(x)));
}
__device__ __forceinline__ float sigf(float x) {
  return 1.f / (1.f + expf(-x));
}

struct GArgs {
  const bf16* A; const float* Af; const bf16* A2;
  long lda, lda2; int ksplit;
  const bf16* Bt;
  int M, N, K, t;
  const float *b_q1, *b_ghh, *b_ag, *b_p1, *b_pm, *b_ps;
  const bf16* obs_pre;
  bf16 *hid_q, *a_buf, *out_bf;
  float *gh, *dout;
};

// EPI: 0 = store bf16 raw (obs_pre precompute)
//      1 = K1: [hid_q w/ obs_pre+elu (cols<H) | gh raw (cols>=H)]
//      3 = aggr: elu -> a_buf (split-K A: z_bf then act)
//      5 = elu + bias -> bf16 (p_hid tail)
//      6 = p-heads: [p_loc | softplus p_scale] -> d_out  (M = T*B rows)
template <int BM, int BN, int EPI, bool AF32>
__global__ __launch_bounds__(256) void gemm_k(GArgs g) {
  constexpr int BK = 32;
  constexpr int WTM = BM / 2, WTN = BN / 2;
  constexpr int MR = WTM / 16, NR = WTN / 16;
  constexpr int CA = BM * 4 / 256, CB = BN * 4 / 256;
  __shared__ bf16 sA[BM * BK];
  __shared__ bf16 sB[BN * BK];
  const int nbm = g.M / BM;
  const int bm = blockIdx.x % nbm, bn = blockIdx.x / nbm;
  const int m0 = bm * BM, n0 = bn * BN;
  const int tid = threadIdx.x;
  const int wid = tid >> 6, lane = tid & 63;
  const int wm = wid & 1, wn = wid >> 1;
  const int lr = lane & 15, lk = lane >> 4;

  f32x4 acc[MR][NR] = {};

  for (int k0 = 0; k0 < g.K; k0 += BK) {
    __syncthreads();
    if constexpr (AF32) {
#pragma unroll
      for (int i = 0; i < CA; i++) {
        int c = tid + i * 256, row = c >> 2, kc = c & 3;
        const float* s = g.Af + (long)(m0 + row) * g.lda + k0 + kc * 8;
        float4 v0 = *(const float4*)s;
        float4 v1 = *(const float4*)(s + 4);
        bf16x8 p;
        p[0] = (bf16)v0.x; p[1] = (bf16)v0.y; p[2] = (bf16)v0.z; p[3] = (bf16)v0.w;
        p[4] = (bf16)v1.x; p[5] = (bf16)v1.y; p[6] = (bf16)v1.z; p[7] = (bf16)v1.w;
        *(bf16x8*)&sA[c * 8] = p;
      }
    } else {
#pragma unroll
      for (int i = 0; i < CA; i++) {
        int c = tid + i * 256, row = c >> 2, kc = c & 3;
        const bf16* s;
        if (EPI == 3 && k0 >= g.ksplit)
          s = g.A2 + (long)(m0 + row) * g.lda2 + (k0 - g.ksplit) + kc * 8;
        else
          s = g.A + (long)(m0 + row) * g.lda + k0 + kc * 8;
        GLL16(s, &sA[c * 8]);
      }
    }
#pragma unroll
    for (int i = 0; i < CB; i++) {
      int c = tid + i * 256, row = c >> 2, kc = c & 3;
      GLL16(g.Bt + (long)(n0 + row) * g.K + k0 + kc * 8, &sB[c * 8]);
    }
    __syncthreads();
    bf16x8 af[MR];
#pragma unroll
    for (int mi = 0; mi < MR; mi++)
      af[mi] = *(const bf16x8*)&sA[(wm * WTM + mi * 16 + lr) * BK + lk * 8];
#pragma unroll
    for (int nj = 0; nj < NR; nj++) {
      bf16x8 bfr = *(const bf16x8*)&sB[(wn * WTN + nj * 16 + lr) * BK + lk * 8];
#pragma unroll
      for (int mi = 0; mi < MR; mi++)
        acc[mi][nj] = __builtin_amdgcn_mfma_f32_16x16x32_bf16(af[mi], bfr, acc[mi][nj], 0, 0, 0);
    }
  }

#pragma unroll
  for (int mi = 0; mi < MR; mi++) {
#pragma unroll
    for (int nj = 0; nj < NR; nj++) {
#pragma unroll
      for (int r = 0; r < 4; r++) {
        const int row = m0 + wm * WTM + mi * 16 + lk * 4 + r;
        const int col = n0 + wn * WTN + nj * 16 + lr;
        float v = acc[mi][nj][r];
        if constexpr (EPI == 0) {
          g.out_bf[(long)row * g.N + col] = (bf16)v;
        } else if constexpr (EPI == 1) {
          if (col < HH) {
            float x = v + g.b_q1[col] + (float)g.obs_pre[((long)g.t * BB + row) * HH + col];
            g.hid_q[row * HH + col] = (bf16)eluf(x);
          } else {
            int j = col - HH;
            g.gh[(long)row * 3 * HH + j] = v + g.b_ghh[j];
          }
        } else if constexpr (EPI == 3) {
          g.a_buf[row * HH + col] = (bf16)eluf(v + g.b_ag[col]);
        } else if constexpr (EPI == 5) {
          g.out_bf[(long)row * g.N + col] = (bf16)eluf(v + g.b_p1[col]);
        } else {  // EPI == 6
          int region = col >> 8, j = col & 255;
          float x = v + (region ? g.b_ps[j] : g.b_pm[j]);
          if (region) x = splusf(x);
          g.dout[(region ? OFF_PS : OFF_PL) + (long)row * ZZ + j] = x;
        }
      }
    }
  }
}

// q-heads dual GEMM + rsample fused. A = hid_q [B,H], Bt2 = [qWm^T | qWs^T] (512 rows x K)
// Block: BM=64 rows x 128 j-cols, both loc and scale accumulators.
struct QZArgs {
  const bf16* A; const bf16* Bt2;
  const float *b_qm, *b_qs; const float* eps;
  float* dout; bf16* z_bf; int t;
};
__global__ __launch_bounds__(256) void qz_gemm(QZArgs g) {
  constexpr int BK = 32;
  __shared__ bf16 sA[64 * BK];
  __shared__ bf16 sB[256 * BK];
  const int bm = blockIdx.x & 7, bn = blockIdx.x >> 3;
  const int m0 = bm * 64, n0 = bn * 128;
  const int tid = threadIdx.x;
  const int wid = tid >> 6, lane = tid & 63;
  const int wm = wid & 1, wn = wid >> 1;
  const int lr = lane & 15, lk = lane >> 4;

  f32x4 accL[2][4] = {}, accS[2][4] = {};

  for (int k0 = 0; k0 < HH; k0 += BK) {
    __syncthreads();
    {
      int c = tid, row = c >> 2, kc = c & 3;
      GLL16(g.A + (long)(m0 + row) * HH + k0 + kc * 8, &sA[c * 8]);
    }
#pragma unroll
    for (int i = 0; i < 4; i++) {
      int c = tid + i * 256, row = c >> 2, kc = c & 3;
      int grow = (row < 128) ? (n0 + row) : (256 + n0 + (row - 128));
      GLL16(g.Bt2 + (long)grow * HH + k0 + kc * 8, &sB[c * 8]);
    }
    __syncthreads();
    bf16x8 af[2];
#pragma unroll
    for (int mi = 0; mi < 2; mi++)
      af[mi] = *(const bf16x8*)&sA[(wm * 32 + mi * 16 + lr) * BK + lk * 8];
#pragma unroll
    for (int nj = 0; nj < 4; nj++) {
      bf16x8 bL = *(const bf16x8*)&sB[(wn * 64 + nj * 16 + lr) * BK + lk * 8];
      bf16x8 bS = *(const bf16x8*)&sB[(128 + wn * 64 + nj * 16 + lr) * BK + lk * 8];
#pragma unroll
      for (int mi = 0; mi < 2; mi++) {
        accL[mi][nj] = __builtin_amdgcn_mfma_f32_16x16x32_bf16(af[mi], bL, accL[mi][nj], 0, 0, 0);
        accS[mi][nj] = __builtin_amdgcn_mfma_f32_16x16x32_bf16(af[mi], bS, accS[mi][nj], 0, 0, 0);
      }
    }
  }

#pragma unroll
  for (int mi = 0; mi < 2; mi++) {
#pragma unroll
    for (int nj = 0; nj < 4; nj++) {
#pragma unroll
      for (int r = 0; r < 4; r++) {
        const int row = m0 + wm * 32 + mi * 16 + lk * 4 + r;
        const int j = n0 + wn * 64 + nj * 16 + lr;
        long o = ((long)g.t * BB + row) * ZZ + j;
        float loc = accL[mi][nj][r] + g.b_qm[j];
        float sc = splusf(accS[mi][nj][r] + g.b_qs[j]);
        float z = loc + sc * g.eps[o];
        g.dout[OFF_QL + o] = loc;
        g.dout[OFF_QS + o] = sc;
        g.dout[OFF_ZQ + o] = z;
        g.z_bf[row * ZZ + j] = (bf16)z;
      }
    }
  }
}

// Wih GEMM + full GRU gate fusion. Bt = Wih^T [3072 rows x K=1024].
// Block: BM=64 rows x 64 j-cols x 3 gates. Reads gh (fp32) + h_bf; writes h_bf + beliefs.
struct GRUArgs {
  const bf16* A; const bf16* Bt;
  const float* b_gih; const float* gh;
  bf16* h_bf; float* dout; int t;
};
__global__ __launch_bounds__(256) void gru_gemm(GRUArgs g) {
  constexpr int BK = 32;
  __shared__ bf16 sA[64 * BK];
  __shared__ bf16 sB[192 * BK];
  const int bm = blockIdx.x & 7, bn = blockIdx.x >> 3;
  const int m0 = bm * 64, n0 = bn * 64;
  const int tid = threadIdx.x;
  const int wid = tid >> 6, lane = tid & 63;
  const int wm = wid & 1, wn = wid >> 1;
  const int lr = lane & 15, lk = lane >> 4;

  f32x4 acc[2][3][2] = {};

  for (int k0 = 0; k0 < HH; k0 += BK) {
    __syncthreads();
    {
      int c = tid, row = c >> 2, kc = c & 3;
      GLL16(g.A + (long)(m0 + row) * HH + k0 + kc * 8, &sA[c * 8]);
    }
#pragma unroll
    for (int i = 0; i < 3; i++) {
      int c = tid + i * 256, row = c >> 2, kc = c & 3;
      int gate = row >> 6, jr = row & 63;
      GLL16(g.Bt + (long)(gate * HH + n0 + jr) * HH + k0 + kc * 8, &sB[c * 8]);
    }
    __syncthreads();
    bf16x8 af[2];
#pragma unroll
    for (int mi = 0; mi < 2; mi++)
      af[mi] = *(const bf16x8*)&sA[(wm * 32 + mi * 16 + lr) * BK + lk * 8];
#pragma unroll
    for (int gt = 0; gt < 3; gt++) {
#pragma unroll
      for (int nj = 0; nj < 2; nj++) {
        bf16x8 bfr = *(const bf16x8*)&sB[(gt * 64 + wn * 32 + nj * 16 + lr) * BK + lk * 8];
#pragma unroll
        for (int mi = 0; mi < 2; mi++)
          acc[mi][gt][nj] = __builtin_amdgcn_mfma_f32_16x16x32_bf16(af[mi], bfr, acc[mi][gt][nj], 0, 0, 0);
      }
    }
  }

#pragma unroll
  for (int mi = 0; mi < 2; mi++) {
#pragma unroll
    for (int nj = 0; nj < 2; nj++) {
#pragma unroll
      for (int r = 0; r < 4; r++) {
        const int row = m0 + wm * 32 + mi * 16 + lk * 4 + r;
        const int j = n0 + wn * 32 + nj * 16 + lr;
        const long gb = (long)row * 3 * HH + j;
        float gir = acc[mi][0][nj][r] + g.b_gih[j];
        float giz = acc[mi][1][nj][r] + g.b_gih[HH + j];
        float gin = acc[mi][2][nj][r] + g.b_gih[2 * HH + j];
        float rr = sigf(gir + g.gh[gb]);
        float zz = sigf(giz + g.gh[gb + HH]);
        float nn = tanhf(gin + rr * g.gh[gb + 2 * HH]);
        float h = (float)g.h_bf[row * HH + j];
        float hn = (1.f - zz) * nn + zz * h;
        g.h_bf[row * HH + j] = (bf16)hn;
        g.dout[(long)(g.t + 1) * BB * HH + (long)row * HH + j] = hn;
      }
    }
  }
}

// dst[n*K + k] = bf16(src[(k + k_off)*ld + n]); grid (N/32, K/32), block (32,8)
__global__ void transpose_cvt(const float* __restrict__ src, bf16* __restrict__ dst,
                              int K, int N, int ld, int k_off) {
  __shared__ float tile[32][33];
  const int nb = blockIdx.x * 32, kb = blockIdx.y * 32;
  const int tx = threadIdx.x, ty = threadIdx.y;
#pragma unroll
  for (int j = 0; j < 32; j += 8)
    tile[ty + j][tx] = src[(long)(kb + ty + j + k_off) * ld + nb + tx];
  __syncthreads();
#pragma unroll
  for (int j = 0; j < 32; j += 8)
    dst[(long)(nb + ty + j) * K + kb + tx] = (bf16)tile[tx][ty + j];
}

__global__ void cvt_bf16(const float* __restrict__ src, bf16* __restrict__ dst, long n) {
  long i = ((long)blockIdx.x * blockDim.x + threadIdx.x) * 4;
  if (i < n) {
    float4 v = *(const float4*)(src + i);
    dst[i] = (bf16)v.x; dst[i + 1] = (bf16)v.y;
    dst[i + 2] = (bf16)v.z; dst[i + 3] = (bf16)v.w;
  }
}

__global__ void init_k(bf16* hbf, float* dout) {
  int i = blockIdx.x * 256 + threadIdx.x;
  hbf[i] = (bf16)0.f;
  dout[i] = 0.f;  // beliefs[0] = h0 = 0
}

extern "C" void kernel_launch(void* const* d_in, const int* in_sizes, int n_in,
                              void* d_out, int out_size, void* d_ws, size_t ws_size,
                              hipStream_t stream) {
  const float* obs  = (const float*)d_in[0];
  const float* act  = (const float*)d_in[1];
  const float* eps  = (const float*)d_in[2];
  const float* aggrW = (const float*)d_in[3];
  const float* aggrB = (const float*)d_in[4];
  const float* gWih = (const float*)d_in[5];
  const float* gWhh = (const float*)d_in[6];
  const float* gbih = (const float*)d_in[7];
  const float* gbhh = (const float*)d_in[8];
  const float* qW1  = (const float*)d_in[9];
  const float* qb1  = (const float*)d_in[10];
  const float* qWm  = (const float*)d_in[11];
  const float* qbm  = (const float*)d_in[12];
  const float* qWs  = (const float*)d_in[13];
  const float* qbs  = (const float*)d_in[14];
  const float* pW1  = (const float*)d_in[15];
  const float* pb1  = (const float*)d_in[16];
  const float* pWm  = (const float*)d_in[17];
  const float* pbm  = (const float*)d_in[18];
  const float* pWs  = (const float*)d_in[19];
  const float* pbs  = (const float*)d_in[20];
  float* dout = (float*)d_out;

  char* w = (char*)d_ws;
  size_t off = 0;
  auto alloc = [&](size_t bytes) -> char* {
    char* r = w + off;
    off = (off + bytes + 255) & ~(size_t)255;
    return r;
  };
  bf16* WT_qobs = (bf16*)alloc((size_t)XX * HH * 2);        // q_W1[:X]^T
  bf16* WT_h   = (bf16*)alloc((size_t)4096 * 1024 * 2);     // [qW1[X:] | Whh]^T
  bf16* WT_qh  = (bf16*)alloc((size_t)512 * 1024 * 2);      // [qWm | qWs]^T
  bf16* WT_ag  = (bf16*)alloc((size_t)1024 * 320 * 2);      // aggr_W^T
  bf16* WT_ih  = (bf16*)alloc((size_t)3072 * 1024 * 2);     // Wih^T
  bf16* WT_p1  = (bf16*)alloc((size_t)1024 * 1024 * 2);     // pW1^T
  bf16* WT_ph  = (bf16*)alloc((size_t)512 * 1024 * 2);      // [pWm | pWs]^T
  bf16* obs_pre = (bf16*)alloc((size_t)TT * BB * HH * 2);   // aliased by p_hid after loop
  bf16* p_hid  = obs_pre;
  bf16* act_bf = (bf16*)alloc((size_t)TT * BB * AA * 2);
  bf16* h_bf   = (bf16*)alloc((size_t)BB * HH * 2);
  bf16* hid_q  = (bf16*)alloc((size_t)BB * HH * 2);
  bf16* z_bf   = (bf16*)alloc((size_t)BB * ZZ * 2);
  bf16* a_buf  = (bf16*)alloc((size_t)BB * HH * 2);
  float* gh_f  = (float*)alloc((size_t)BB * 3 * HH * 4);
  (void)ws_size; (void)in_sizes; (void)n_in; (void)out_size;

  dim3 tb(32, 8);
  transpose_cvt<<<dim3(32, 32), tb, 0, stream>>>(qW1, WT_qobs, 1024, 1024, 1024, 0);
  transpose_cvt<<<dim3(32, 32), tb, 0, stream>>>(qW1, WT_h, 1024, 1024, 1024, 1024);
  transpose_cvt<<<dim3(96, 32), tb, 0, stream>>>(gWhh, WT_h + 1024 * 1024, 1024, 3072, 3072, 0);
  transpose_cvt<<<dim3(8, 32), tb, 0, stream>>>(qWm, WT_qh, 1024, 256, 256, 0);
  transpose_cvt<<<dim3(8, 32), tb, 0, stream>>>(qWs, WT_qh + 256 * 1024, 1024, 256, 256, 0);
  transpose_cvt<<<dim3(32, 10), tb, 0, stream>>>(aggrW, WT_ag, 320, 1024, 1024, 0);
  transpose_cvt<<<dim3(96, 32), tb, 0, stream>>>(gWih, WT_ih, 1024, 3072, 3072, 0);
  transpose_cvt<<<dim3(32, 32), tb, 0, stream>>>(pW1, WT_p1, 1024, 1024, 1024, 0);
  transpose_cvt<<<dim3(8, 32), tb, 0, stream>>>(pWm, WT_ph, 1024, 256, 256, 0);
  transpose_cvt<<<dim3(8, 32), tb, 0, stream>>>(pWs, WT_ph + 256 * 1024, 1024, 256, 256, 0);
  cvt_bf16<<<TT * BB * AA / 4 / 256, 256, 0, stream>>>(act, act_bf, (long)TT * BB * AA);
  init_k<<<BB * HH / 256, 256, 0, stream>>>(h_bf, dout);

  GArgs g{};
  g.b_q1 = qb1; g.b_ghh = gbhh; g.b_ag = aggrB; g.b_p1 = pb1;
  g.b_pm = pbm; g.b_ps = pbs;
  g.obs_pre = obs_pre; g.hid_q = hid_q; g.a_buf = a_buf;
  g.gh = gh_f; g.dout = dout;

  {  // obs_pre = obs @ qW1[:X]  (fully parallel, M = T*B)
    GArgs a = g;
    a.Af = obs; a.lda = XX; a.Bt = WT_qobs;
    a.M = TT * BB; a.N = HH; a.K = XX; a.out_bf = obs_pre;
    gemm_k<128, 128, 0, true><<<(TT * BB / 128) * (HH / 128), 256, 0, stream>>>(a);
  }

  for (int t = 0; t < TT; ++t) {
    {  // K1: h @ [qW1_h | Whh], N=4096 -> hid_q, gh
      GArgs a = g; a.t = t;
      a.A = h_bf; a.lda = HH; a.Bt = WT_h;
      a.M = BB; a.N = 4096; a.K = HH;
      gemm_k<64, 128, 1, false><<<(BB / 64) * (4096 / 128), 256, 0, stream>>>(a);
    }
    {  // K2: q-heads dual + rsample fused
      QZArgs a{hid_q, WT_qh, qbm, qbs, eps, dout, z_bf, t};
      qz_gemm<<<8 * 2, 256, 0, stream>>>(a);
    }
    {  // K3: [z_q | act_t] @ aggr_W -> elu -> a_buf, K=320
      GArgs a = g; a.t = t;
      a.A = z_bf; a.lda = ZZ;
      a.A2 = act_bf + (size_t)t * BB * AA; a.lda2 = AA; a.ksplit = ZZ;
      a.Bt = WT_ag; a.M = BB; a.N = 1024; a.K = ZZ + AA;
      gemm_k<64, 128, 3, false><<<(BB / 64) * (1024 / 128), 256, 0, stream>>>(a);
    }
    {  // K4: a @ Wih + full GRU fused -> h_bf, beliefs
      GRUArgs a{a_buf, WT_ih, gbih, gh_f, h_bf, dout, t};
      gru_gemm<<<8 * 16, 256, 0, stream>>>(a);
    }
  }

  {  // p_hid = elu(beliefs[0:T*B] @ pW1 + b1)  (batched, A = fp32 beliefs)
    GArgs a = g;
    a.Af = dout; a.lda = HH; a.Bt = WT_p1;
    a.M = TT * BB; a.N = HH; a.K = HH; a.out_bf = p_hid;
    gemm_k<128, 128, 5, true><<<(TT * BB / 128) * (HH / 128), 256, 0, stream>>>(a);
  }
  {  // p-heads: p_hid @ [pWm|pWs] -> d_out
    GArgs a = g;
    a.A = p_hid; a.lda = HH; a.Bt = WT_ph;
    a.M = TT * BB; a.N = 512; a.K = HH;
    gemm_k<128, 128, 6, false><<<(TT * BB / 128) * (512 / 128), 256, 0, stream>>>(a);
  }
}